// Round 5
// baseline (925.891 us; speedup 1.0000x reference)
//
#include <hip/hip_runtime.h>
#include <hip/hip_fp16.h>

// GCN: 2x GCNConv + mean-pool + 2 MLP heads.
// Strategy R3b: feature-split fp16 gather (4 MB resident array per pass =
// per-XCD L2 capacity), edge-parallel agg with LDS accumulators over coarse
// dst-buckets (binB/bscan deleted), nt hints on all streaming traffic.
// hh = h * dinv folding removes dinv[src] lookups; bias+leaky fused in agg.
// (R4 fix: nontemporal builtins need scalar/ext-vector types, not int2/float4.)

#define NBUCK 512          // coarse buckets = dst >> 9
#define BCAP  10240        // slack capacity per bucket (mean 8192)
#define CHUNK 4096         // edges per binA block

typedef float vfloat4 __attribute__((ext_vector_type(4)));

__device__ __forceinline__ float leaky(float x) { return x > 0.f ? x : 0.01f * x; }

// --- Pass A: bin edges by dst>>9; payload (src | ld<<18, ew) -------------
__global__ __launch_bounds__(256) void
binA_kernel(const int* __restrict__ src, const int* __restrict__ dst,
            const float* __restrict__ ew, int* __restrict__ bucketCursor,
            long long* __restrict__ coarse, int E) {
    __shared__ int lhist[NBUCK], lbase[NBUCK], lcur[NBUCK], gbase[NBUCK];
    __shared__ int tmp[256];
    __shared__ long long stag[CHUNK];
    __shared__ unsigned short sbuck[CHUNK];
    int t = threadIdx.x;
    int base = blockIdx.x * CHUNK;
    for (int b = t; b < NBUCK; b += 256) { lhist[b] = 0; lcur[b] = 0; }
    __syncthreads();
    int n = min(CHUNK, E - base);
    int myDst[16], mySrc[16]; float myEw[16];
#pragma unroll
    for (int k = 0; k < 16; ++k) {
        int j = t + k * 256;                       // coalesced
        if (j < n) {
            int d = dst[base + j];
            myDst[k] = d; mySrc[k] = src[base + j]; myEw[k] = ew[base + j];
            atomicAdd(&lhist[d >> 9], 1);
        } else myDst[k] = -1;
    }
    __syncthreads();
    tmp[t] = lhist[2 * t] + lhist[2 * t + 1];
    __syncthreads();
    for (int off = 1; off < 256; off <<= 1) {
        int v = (t >= off) ? tmp[t - off] : 0;
        __syncthreads();
        tmp[t] += v;
        __syncthreads();
    }
    int pb = (t == 0) ? 0 : tmp[t - 1];
    lbase[2 * t] = pb;
    lbase[2 * t + 1] = pb + lhist[2 * t];
    __syncthreads();
    for (int b = t; b < NBUCK; b += 256) {
        int c = lhist[b];
        gbase[b] = c ? atomicAdd(&bucketCursor[b], c) : 0;
    }
    for (int k = 0; k < 16; ++k) {
        int d = myDst[k];
        if (d >= 0) {
            int b = d >> 9;
            int p = lbase[b] + atomicAdd(&lcur[b], 1);
            unsigned int lo = (unsigned int)(mySrc[k] | ((d & 511) << 18));
            stag[p] = (long long)(((unsigned long long)__float_as_uint(myEw[k]) << 32) | lo);
            sbuck[p] = (unsigned short)b;
        }
    }
    __syncthreads();
    for (int j = t; j < n; j += 256) {
        int b = sbuck[j];
        __builtin_nontemporal_store(stag[j],
            &coarse[(size_t)b * BCAP + gbase[b] + (j - lbase[b])]);
    }
}

// --- degree per bucket -> dinv -------------------------------------------
__global__ __launch_bounds__(256) void
deg_kernel(const int* __restrict__ bucketCursor, const long long* __restrict__ coarse,
           float* __restrict__ dinv) {
    __shared__ float ldeg[NBUCK];
    int b = blockIdx.x, t = threadIdx.x;
    for (int i = t; i < NBUCK; i += 256) ldeg[i] = 0.f;
    __syncthreads();
    int cnt = bucketCursor[b];
    const long long* cb = coarse + (size_t)b * BCAP;
    for (int j = t; j < cnt; j += 256) {
        long long ev = __builtin_nontemporal_load(cb + j);
        int x = (int)ev;
        float w = __uint_as_float((unsigned int)((unsigned long long)ev >> 32));
        atomicAdd(&ldeg[(x >> 18) & 511], w);
    }
    __syncthreads();
    for (int i = t; i < NBUCK; i += 256)
        dinv[b * NBUCK + i] = rsqrtf(1.0f + ldeg[i]);   // +1 = self-loop
}

// --- node pass 1: hh1 = (X@W1)*dinv, fp16, feature-split -----------------
__global__ void node1_kernel(const float* __restrict__ X, const float* __restrict__ W1,
                             const float* __restrict__ dinv,
                             _Float16* __restrict__ hhA, _Float16* __restrict__ hhB, int N) {
    __shared__ float w[48];
    if (threadIdx.x < 48) w[threadIdx.x] = W1[threadIdx.x];
    __syncthreads();
    int i = blockIdx.x * blockDim.x + threadIdx.x;
    if (i >= N) return;
    float di = dinv[i];
    float x0 = X[3 * i], x1 = X[3 * i + 1], x2 = X[3 * i + 2];
    union { _Float16 h[8]; vfloat4 v; } ua, ub;
#pragma unroll
    for (int k = 0; k < 8; ++k)
        ua.h[k] = (_Float16)((x0 * w[k] + x1 * w[16 + k] + x2 * w[32 + k]) * di);
#pragma unroll
    for (int k = 0; k < 8; ++k)
        ub.h[k] = (_Float16)((x0 * w[8 + k] + x1 * w[24 + k] + x2 * w[40 + k]) * di);
    ((vfloat4*)hhA)[i] = ua.v;
    ((vfloat4*)hhB)[i] = ub.v;
}

// --- edge-parallel half-feature aggregation over one coarse bucket -------
// out[i] = leaky( dinv_i*(sum_e ew*hh[src] + hh[i]) + bias8 )
__global__ __launch_bounds__(512) void
agg_kernel(const int* __restrict__ bucketCursor, const long long* __restrict__ coarse,
           const float* __restrict__ dinv, const _Float16* __restrict__ hh,
           const float* __restrict__ bias8, float* __restrict__ out) {
    __shared__ float acc[NBUCK * 9];                 // stride 9: bank-spread
    int b = blockIdx.x, t = threadIdx.x;
    for (int i = t; i < NBUCK * 9; i += 512) acc[i] = 0.f;
    __syncthreads();
    int cnt = bucketCursor[b];
    const long long* cb = coarse + (size_t)b * BCAP;
    int j = t;
    long long ev = (j < cnt) ? __builtin_nontemporal_load(cb + j) : 0;
    while (j < cnt) {
        int jn = j + 512;
        long long evn = (jn < cnt) ? __builtin_nontemporal_load(cb + jn) : 0;
        int x = (int)ev;
        float w = __uint_as_float((unsigned int)((unsigned long long)ev >> 32));
        int s = x & 0x3FFFF, ld = (x >> 18) & 511;
        vfloat4 raw = *(const vfloat4*)(hh + (size_t)s * 8);   // cached: resident array
        const _Float16* hf = (const _Float16*)&raw;
        float* a = &acc[ld * 9];
#pragma unroll
        for (int k = 0; k < 8; ++k) atomicAdd(&a[k], (float)hf[k] * w);
        ev = evn; j = jn;
    }
    __syncthreads();
    // epilogue: one node per thread (blockDim 512 == NBUCK)
    int node = b * NBUCK + t;
    float di = dinv[node];
    vfloat4 raw = *(const vfloat4*)(hh + (size_t)node * 8);
    const _Float16* hf = (const _Float16*)&raw;
    float o[8];
#pragma unroll
    for (int k = 0; k < 8; ++k) {
        float v = di * (acc[t * 9 + k] + (float)hf[k]);
        o[k] = leaky(v + bias8[k]);
    }
    float* op = out + (size_t)node * 8;
    vfloat4 o0 = {o[0], o[1], o[2], o[3]};
    vfloat4 o1 = {o[4], o[5], o[6], o[7]};
    __builtin_nontemporal_store(o0, (vfloat4*)op);
    __builtin_nontemporal_store(o1, (vfloat4*)(op + 4));
}

// --- node pass 2: h2 = x1@W2; hh2 = h2*dinv, fp16, split -----------------
__global__ void node2_kernel(const float* __restrict__ W2, const float* __restrict__ dinv,
                             const float* __restrict__ xA, const float* __restrict__ xB,
                             _Float16* __restrict__ hhA, _Float16* __restrict__ hhB, int N) {
    __shared__ float w[256];
    w[threadIdx.x] = W2[threadIdx.x];                // blockDim == 256
    __syncthreads();
    int i = blockIdx.x * blockDim.x + threadIdx.x;
    if (i >= N) return;
    float x[16];
    vfloat4 a0 = ((const vfloat4*)xA)[2 * i], a1 = ((const vfloat4*)xA)[2 * i + 1];
    vfloat4 b0 = ((const vfloat4*)xB)[2 * i], b1 = ((const vfloat4*)xB)[2 * i + 1];
#pragma unroll
    for (int k = 0; k < 4; ++k) {
        x[k] = a0[k]; x[4 + k] = a1[k]; x[8 + k] = b0[k]; x[12 + k] = b1[k];
    }
    float di = dinv[i];
    union { _Float16 h[8]; vfloat4 v; } ua, ub;
#pragma unroll
    for (int f = 0; f < 8; ++f) {
        float s = 0.f;
#pragma unroll
        for (int k = 0; k < 16; ++k) s += x[k] * w[k * 16 + f];
        ua.h[f] = (_Float16)(s * di);
    }
#pragma unroll
    for (int f = 0; f < 8; ++f) {
        float s = 0.f;
#pragma unroll
        for (int k = 0; k < 16; ++k) s += x[k] * w[k * 16 + 8 + f];
        ub.h[f] = (_Float16)(s * di);
    }
    ((vfloat4*)hhA)[i] = ua.v;
    ((vfloat4*)hhB)[i] = ub.v;
}

// --- tiny MLP head: 16 ->16 ->16 ->2 -------------------------------------
__device__ void head_mlp(const float* pooled,
                         const float* __restrict__ Wa, const float* __restrict__ ba,
                         const float* __restrict__ Wb, const float* __restrict__ bb,
                         const float* __restrict__ Wc, const float* __restrict__ bc,
                         float* o) {
    float t[16], u[16];
#pragma unroll
    for (int f = 0; f < 16; ++f) {
        float a = ba[f];
        for (int k = 0; k < 16; ++k) a += pooled[k] * Wa[k * 16 + f];
        t[f] = leaky(a);
    }
#pragma unroll
    for (int f = 0; f < 16; ++f) {
        float a = bb[f];
        for (int k = 0; k < 16; ++k) a += t[k] * Wb[k * 16 + f];
        u[f] = leaky(a);
    }
    float o0 = bc[0], o1 = bc[1];
    for (int k = 0; k < 16; ++k) { o0 += u[k] * Wc[2 * k]; o1 += u[k] * Wc[2 * k + 1]; }
    o[0] = o0; o[1] = o1;
}

// --- pool (block per graph) + heads; y already has leaky+b2 applied ------
__global__ void pool_head_kernel(const float* __restrict__ yA, const float* __restrict__ yB,
                                 const int* __restrict__ batching, int N,
                                 const float* __restrict__ Wp1, const float* __restrict__ bp1,
                                 const float* __restrict__ Wp2, const float* __restrict__ bp2,
                                 const float* __restrict__ Wp3, const float* __restrict__ bp3,
                                 const float* __restrict__ Wt1, const float* __restrict__ bt1,
                                 const float* __restrict__ Wt2, const float* __restrict__ bt2,
                                 const float* __restrict__ Wt3, const float* __restrict__ bt3,
                                 float* __restrict__ out) {
    int g = blockIdx.x;
    __shared__ int bounds[2];
    if (threadIdx.x < 2) {
        int v = g + (int)threadIdx.x;
        int lo = 0, hi = N;
        while (lo < hi) { int m = (lo + hi) >> 1; if (batching[m] < v) lo = m + 1; else hi = m; }
        bounds[threadIdx.x] = lo;
    }
    __syncthreads();
    int lo = bounds[0], hi = bounds[1];
    int f = threadIdx.x & 15, r = threadIdx.x >> 4;    // 16 rows x 16 features
    const float* yb = (f < 8) ? yA : yB;
    int fo = f & 7;
    float acc = 0.f;
    for (int i = lo + r; i < hi; i += 16) acc += yb[(size_t)i * 8 + fo];
    __shared__ float red[16][17];
    red[r][f] = acc;
    __syncthreads();
    __shared__ float pooled[16];
    if (r == 0) {
        float s = 0.f;
#pragma unroll
        for (int k = 0; k < 16; ++k) s += red[k][f];
        pooled[f] = s / fmaxf((float)(hi - lo), 1.0f);
    }
    __syncthreads();
    if (threadIdx.x == 0) {
        float o[2];
        head_mlp(pooled, Wp1, bp1, Wp2, bp2, Wp3, bp3, o);
        out[4 * g + 0] = o[0]; out[4 * g + 1] = o[1];
    } else if (threadIdx.x == 1) {
        float o[2];
        head_mlp(pooled, Wt1, bt1, Wt2, bt2, Wt3, bt3, o);
        out[4 * g + 2] = o[0]; out[4 * g + 3] = o[1];
    }
}

extern "C" void kernel_launch(void* const* d_in, const int* in_sizes, int n_in,
                              void* d_out, int out_size, void* d_ws, size_t ws_size,
                              hipStream_t stream) {
    const float* X        = (const float*)d_in[0];
    const int*   ei       = (const int*)d_in[1];
    const float* ew       = (const float*)d_in[2];
    const int*   batching = (const int*)d_in[3];
    const float* W1  = (const float*)d_in[5];  const float* b1  = (const float*)d_in[6];
    const float* W2  = (const float*)d_in[7];  const float* b2  = (const float*)d_in[8];
    const float* Wp1 = (const float*)d_in[9];  const float* bp1 = (const float*)d_in[10];
    const float* Wp2 = (const float*)d_in[11]; const float* bp2 = (const float*)d_in[12];
    const float* Wp3 = (const float*)d_in[13]; const float* bp3 = (const float*)d_in[14];
    const float* Wt1 = (const float*)d_in[15]; const float* bt1 = (const float*)d_in[16];
    const float* Wt2 = (const float*)d_in[17]; const float* bt2 = (const float*)d_in[18];
    const float* Wt3 = (const float*)d_in[19]; const float* bt3 = (const float*)d_in[20];

    const int N = in_sizes[3];        // 262144 = 512 * 512
    const int E = in_sizes[2];        // 4194304
    const int G = out_size / 4;       // 1024
    const int* src = ei;
    const int* dst = ei + E;

    char* ws = (char*)d_ws;
    size_t off = 0;
    long long* coarse = (long long*)(ws + off); off += (size_t)NBUCK * BCAP * 8; // 41.9 MB
    int*   bucketCursor = (int*)(ws + off);   off += NBUCK * 4;
    float* dinv = (float*)(ws + off);         off += (size_t)N * 4;             // 1 MB
    _Float16* hhA = (_Float16*)(ws + off);    off += (size_t)N * 16;            // 4 MB
    _Float16* hhB = (_Float16*)(ws + off);    off += (size_t)N * 16;            // 4 MB
    float* xA = (float*)(ws + off);           off += (size_t)N * 32;            // 8 MB (x1a -> y2a)
    float* xB = (float*)(ws + off);           off += (size_t)N * 32;            // 8 MB (x1b -> y2b)
    float* out = (float*)d_out;

    (void)hipMemsetAsync(bucketCursor, 0, NBUCK * 4, stream);

    const int tb = 256;
    binA_kernel<<<(E + CHUNK - 1) / CHUNK, tb, 0, stream>>>(src, dst, ew, bucketCursor, coarse, E);
    deg_kernel<<<NBUCK, tb, 0, stream>>>(bucketCursor, coarse, dinv);
    node1_kernel<<<(N + tb - 1) / tb, tb, 0, stream>>>(X, W1, dinv, hhA, hhB, N);
    agg_kernel<<<NBUCK, 512, 0, stream>>>(bucketCursor, coarse, dinv, hhA, b1,     xA);
    agg_kernel<<<NBUCK, 512, 0, stream>>>(bucketCursor, coarse, dinv, hhB, b1 + 8, xB);
    node2_kernel<<<(N + tb - 1) / tb, tb, 0, stream>>>(W2, dinv, xA, xB, hhA, hhB, N);
    agg_kernel<<<NBUCK, 512, 0, stream>>>(bucketCursor, coarse, dinv, hhA, b2,     xA);
    agg_kernel<<<NBUCK, 512, 0, stream>>>(bucketCursor, coarse, dinv, hhB, b2 + 8, xB);
    pool_head_kernel<<<G, tb, 0, stream>>>(xA, xB, batching, N,
                                           Wp1, bp1, Wp2, bp2, Wp3, bp3,
                                           Wt1, bt1, Wt2, bt2, Wt3, bt3, out);
}

// Round 6
// 561.914 us; speedup vs baseline: 1.6477x; 1.6477x over previous
//
#include <hip/hip_runtime.h>
#include <hip/hip_fp16.h>

// GCN: 2x GCNConv + mean-pool + 2 MLP heads.
// Strategy R5: fp16 feature-split resident gather (R3's win) + per-node
// register-accum agg over fine CSR (R2's structure) -> zero atomics in the
// feature path. binB (fine sort) is back and also emits row[] + dinv[].
// R5 lesson: edge-parallel LDS-atomic agg = 33.5M ds-atomics/pass = 178 us.

#define NBUCK 512          // coarse buckets = dst >> 9
#define BCAP  10240        // slack capacity per bucket (mean 8192)
#define CHUNK 4096         // edges per binA block

typedef float  vfloat4 __attribute__((ext_vector_type(4)));
typedef _Float16 vhalf4 __attribute__((ext_vector_type(4)));

__device__ __forceinline__ float leaky(float x) { return x > 0.f ? x : 0.01f * x; }

// --- Pass A: bin edges by dst>>9; payload (src | ld<<18, ew) -------------
__global__ __launch_bounds__(256) void
binA_kernel(const int* __restrict__ src, const int* __restrict__ dst,
            const float* __restrict__ ew, int* __restrict__ bucketCursor,
            long long* __restrict__ coarse, int E) {
    __shared__ int lhist[NBUCK], lbase[NBUCK], lcur[NBUCK], gbase[NBUCK];
    __shared__ int tmp[256];
    __shared__ long long stag[CHUNK];
    __shared__ unsigned short sbuck[CHUNK];
    int t = threadIdx.x;
    int base = blockIdx.x * CHUNK;
    for (int b = t; b < NBUCK; b += 256) { lhist[b] = 0; lcur[b] = 0; }
    __syncthreads();
    int n = min(CHUNK, E - base);
    int myDst[16], mySrc[16]; float myEw[16];
#pragma unroll
    for (int k = 0; k < 16; ++k) {
        int j = t + k * 256;                       // coalesced
        if (j < n) {
            int d = dst[base + j];
            myDst[k] = d; mySrc[k] = src[base + j]; myEw[k] = ew[base + j];
            atomicAdd(&lhist[d >> 9], 1);
        } else myDst[k] = -1;
    }
    __syncthreads();
    tmp[t] = lhist[2 * t] + lhist[2 * t + 1];
    __syncthreads();
    for (int off = 1; off < 256; off <<= 1) {
        int v = (t >= off) ? tmp[t - off] : 0;
        __syncthreads();
        tmp[t] += v;
        __syncthreads();
    }
    int pb = (t == 0) ? 0 : tmp[t - 1];
    lbase[2 * t] = pb;
    lbase[2 * t + 1] = pb + lhist[2 * t];
    __syncthreads();
    for (int b = t; b < NBUCK; b += 256) {
        int c = lhist[b];
        gbase[b] = c ? atomicAdd(&bucketCursor[b], c) : 0;
    }
    for (int k = 0; k < 16; ++k) {
        int d = myDst[k];
        if (d >= 0) {
            int b = d >> 9;
            int p = lbase[b] + atomicAdd(&lcur[b], 1);
            unsigned int lo = (unsigned int)(mySrc[k] | ((d & 511) << 18));
            stag[p] = (long long)(((unsigned long long)__float_as_uint(myEw[k]) << 32) | lo);
            sbuck[p] = (unsigned short)b;
        }
    }
    __syncthreads();
    for (int j = t; j < n; j += 256) {
        int b = sbuck[j];
        __builtin_nontemporal_store(stag[j],
            &coarse[(size_t)b * BCAP + gbase[b] + (j - lbase[b])]);
    }
}

// --- scan bucket counts -> bucket bases (1 block x 512) ------------------
__global__ void bscan_kernel(const int* __restrict__ bucketCursor,
                             int* __restrict__ bucketBase, int* __restrict__ row,
                             int N, int E) {
    __shared__ int s[NBUCK];
    int t = threadIdx.x;
    int v = bucketCursor[t];
    s[t] = v;
    __syncthreads();
    for (int off = 1; off < NBUCK; off <<= 1) {
        int x = (t >= off) ? s[t - off] : 0;
        __syncthreads();
        s[t] += x;
        __syncthreads();
    }
    bucketBase[t] = s[t] - v;
    if (t == 0) row[N] = E;
}

// --- Pass B: fine sort within bucket; emit edata (src,ew), row, dinv -----
__global__ __launch_bounds__(256) void
binB_kernel(const int* __restrict__ bucketCursor, const int* __restrict__ bucketBase,
            const long long* __restrict__ coarse, long long* __restrict__ edata,
            int* __restrict__ row, float* __restrict__ dinv, int N) {
    __shared__ int lhist[NBUCK], loff[NBUCK], lcur[NBUCK];
    __shared__ float ldeg[NBUCK];
    __shared__ int tmp[256];
    int b = blockIdx.x, t = threadIdx.x;
    for (int i = t; i < NBUCK; i += 256) { lhist[i] = 0; lcur[i] = 0; ldeg[i] = 0.f; }
    __syncthreads();
    int cnt = bucketCursor[b];
    const long long* cb = coarse + (size_t)b * BCAP;
    for (int j = t; j < cnt; j += 256) {
        long long e = __builtin_nontemporal_load(cb + j);
        int ld = ((int)e >> 18) & 511;
        atomicAdd(&lhist[ld], 1);
        atomicAdd(&ldeg[ld], __uint_as_float((unsigned)((unsigned long long)e >> 32)));
    }
    __syncthreads();
    tmp[t] = lhist[2 * t] + lhist[2 * t + 1];
    __syncthreads();
    for (int off = 1; off < 256; off <<= 1) {
        int v = (t >= off) ? tmp[t - off] : 0;
        __syncthreads();
        tmp[t] += v;
        __syncthreads();
    }
    int pb = (t == 0) ? 0 : tmp[t - 1];
    loff[2 * t] = pb;
    loff[2 * t + 1] = pb + lhist[2 * t];
    __syncthreads();
    int gb = bucketBase[b];
    for (int i = t; i < NBUCK; i += 256) {
        int node = b * NBUCK + i;
        row[node] = gb + loff[i];
        dinv[node] = rsqrtf(1.0f + ldeg[i]);     // +1 = self-loop
    }
    for (int j = t; j < cnt; j += 256) {
        long long e = __builtin_nontemporal_load(cb + j);
        int x = (int)e;
        int ld = (x >> 18) & 511;
        int pos = gb + loff[ld] + atomicAdd(&lcur[ld], 1);
        // store (src, ew): src plain in low 32
        edata[pos] = (long long)(((unsigned long long)e & 0xFFFFFFFF00000000ull)
                                 | (unsigned)(x & 0x3FFFF));
    }
}

// --- node pass 1: hh1 = (X@W1)*dinv, fp16, feature-split -----------------
__global__ void node1_kernel(const float* __restrict__ X, const float* __restrict__ W1,
                             const float* __restrict__ dinv,
                             _Float16* __restrict__ hhA, _Float16* __restrict__ hhB, int N) {
    __shared__ float w[48];
    if (threadIdx.x < 48) w[threadIdx.x] = W1[threadIdx.x];
    __syncthreads();
    int i = blockIdx.x * blockDim.x + threadIdx.x;
    if (i >= N) return;
    float di = dinv[i];
    float x0 = X[3 * i], x1 = X[3 * i + 1], x2 = X[3 * i + 2];
    union { _Float16 h[8]; vfloat4 v; } ua, ub;
#pragma unroll
    for (int k = 0; k < 8; ++k)
        ua.h[k] = (_Float16)((x0 * w[k] + x1 * w[16 + k] + x2 * w[32 + k]) * di);
#pragma unroll
    for (int k = 0; k < 8; ++k)
        ub.h[k] = (_Float16)((x0 * w[8 + k] + x1 * w[24 + k] + x2 * w[40 + k]) * di);
    ((vfloat4*)hhA)[i] = ua.v;
    ((vfloat4*)hhB)[i] = ub.v;
}

// --- per-node gather agg: 2 lanes/node, 4 feats each, register accum -----
// out[i,f] = leaky( dinv_i*(sum_e ew*hh[src,f] + hh[i,f]) + bias8[f] )
__global__ __launch_bounds__(256) void
agg_kernel(const int* __restrict__ row, const long long* __restrict__ edata,
           const float* __restrict__ dinv, const _Float16* __restrict__ hh,
           const float* __restrict__ bias8, float* __restrict__ out, int N) {
    int t = blockIdx.x * blockDim.x + threadIdx.x;
    int i = t >> 1, l = t & 1;
    if (i >= N) return;
    int beg = row[i], end = row[i + 1];
    const vhalf4* hp = (const vhalf4*)hh;          // 2 entries per node
    vhalf4 self = hp[2 * i + l];
    float a0 = (float)self[0], a1 = (float)self[1], a2 = (float)self[2], a3 = (float)self[3];
    int e = beg;
    for (; e + 2 <= end; e += 2) {                 // 2x unroll for MLP
        long long ev0 = edata[e], ev1 = edata[e + 1];
        int s0 = (int)ev0, s1 = (int)ev1;
        float w0 = __uint_as_float((unsigned)((unsigned long long)ev0 >> 32));
        float w1 = __uint_as_float((unsigned)((unsigned long long)ev1 >> 32));
        vhalf4 g0 = hp[2 * s0 + l];
        vhalf4 g1 = hp[2 * s1 + l];
        a0 += (float)g0[0] * w0; a1 += (float)g0[1] * w0;
        a2 += (float)g0[2] * w0; a3 += (float)g0[3] * w0;
        a0 += (float)g1[0] * w1; a1 += (float)g1[1] * w1;
        a2 += (float)g1[2] * w1; a3 += (float)g1[3] * w1;
    }
    if (e < end) {
        long long ev = edata[e];
        int s = (int)ev;
        float w = __uint_as_float((unsigned)((unsigned long long)ev >> 32));
        vhalf4 g = hp[2 * s + l];
        a0 += (float)g[0] * w; a1 += (float)g[1] * w;
        a2 += (float)g[2] * w; a3 += (float)g[3] * w;
    }
    float di = dinv[i];
    const float* bp = bias8 + 4 * l;
    vfloat4 o = { leaky(di * a0 + bp[0]), leaky(di * a1 + bp[1]),
                  leaky(di * a2 + bp[2]), leaky(di * a3 + bp[3]) };
    __builtin_nontemporal_store(o, (vfloat4*)(out + (size_t)i * 8 + 4 * l));
}

// --- node pass 2: h2 = x1@W2; hh2 = h2*dinv, fp16, split -----------------
__global__ void node2_kernel(const float* __restrict__ W2, const float* __restrict__ dinv,
                             const float* __restrict__ xA, const float* __restrict__ xB,
                             _Float16* __restrict__ hhA, _Float16* __restrict__ hhB, int N) {
    __shared__ float w[256];
    w[threadIdx.x] = W2[threadIdx.x];                // blockDim == 256
    __syncthreads();
    int i = blockIdx.x * blockDim.x + threadIdx.x;
    if (i >= N) return;
    float x[16];
    vfloat4 a0 = ((const vfloat4*)xA)[2 * i], a1 = ((const vfloat4*)xA)[2 * i + 1];
    vfloat4 b0 = ((const vfloat4*)xB)[2 * i], b1 = ((const vfloat4*)xB)[2 * i + 1];
#pragma unroll
    for (int k = 0; k < 4; ++k) {
        x[k] = a0[k]; x[4 + k] = a1[k]; x[8 + k] = b0[k]; x[12 + k] = b1[k];
    }
    float di = dinv[i];
    union { _Float16 h[8]; vfloat4 v; } ua, ub;
#pragma unroll
    for (int f = 0; f < 8; ++f) {
        float s = 0.f;
#pragma unroll
        for (int k = 0; k < 16; ++k) s += x[k] * w[k * 16 + f];
        ua.h[f] = (_Float16)(s * di);
    }
#pragma unroll
    for (int f = 0; f < 8; ++f) {
        float s = 0.f;
#pragma unroll
        for (int k = 0; k < 16; ++k) s += x[k] * w[k * 16 + 8 + f];
        ub.h[f] = (_Float16)(s * di);
    }
    ((vfloat4*)hhA)[i] = ua.v;
    ((vfloat4*)hhB)[i] = ub.v;
}

// --- tiny MLP head: 16 ->16 ->16 ->2 -------------------------------------
__device__ void head_mlp(const float* pooled,
                         const float* __restrict__ Wa, const float* __restrict__ ba,
                         const float* __restrict__ Wb, const float* __restrict__ bb,
                         const float* __restrict__ Wc, const float* __restrict__ bc,
                         float* o) {
    float t[16], u[16];
#pragma unroll
    for (int f = 0; f < 16; ++f) {
        float a = ba[f];
        for (int k = 0; k < 16; ++k) a += pooled[k] * Wa[k * 16 + f];
        t[f] = leaky(a);
    }
#pragma unroll
    for (int f = 0; f < 16; ++f) {
        float a = bb[f];
        for (int k = 0; k < 16; ++k) a += t[k] * Wb[k * 16 + f];
        u[f] = leaky(a);
    }
    float o0 = bc[0], o1 = bc[1];
    for (int k = 0; k < 16; ++k) { o0 += u[k] * Wc[2 * k]; o1 += u[k] * Wc[2 * k + 1]; }
    o[0] = o0; o[1] = o1;
}

// --- pool (block per graph) + heads; y already has leaky+b2 applied ------
__global__ void pool_head_kernel(const float* __restrict__ yA, const float* __restrict__ yB,
                                 const int* __restrict__ batching, int N,
                                 const float* __restrict__ Wp1, const float* __restrict__ bp1,
                                 const float* __restrict__ Wp2, const float* __restrict__ bp2,
                                 const float* __restrict__ Wp3, const float* __restrict__ bp3,
                                 const float* __restrict__ Wt1, const float* __restrict__ bt1,
                                 const float* __restrict__ Wt2, const float* __restrict__ bt2,
                                 const float* __restrict__ Wt3, const float* __restrict__ bt3,
                                 float* __restrict__ out) {
    int g = blockIdx.x;
    __shared__ int bounds[2];
    if (threadIdx.x < 2) {
        int v = g + (int)threadIdx.x;
        int lo = 0, hi = N;
        while (lo < hi) { int m = (lo + hi) >> 1; if (batching[m] < v) lo = m + 1; else hi = m; }
        bounds[threadIdx.x] = lo;
    }
    __syncthreads();
    int lo = bounds[0], hi = bounds[1];
    int f = threadIdx.x & 15, r = threadIdx.x >> 4;    // 16 rows x 16 features
    const float* yb = (f < 8) ? yA : yB;
    int fo = f & 7;
    float acc = 0.f;
    for (int i = lo + r; i < hi; i += 16) acc += yb[(size_t)i * 8 + fo];
    __shared__ float red[16][17];
    red[r][f] = acc;
    __syncthreads();
    __shared__ float pooled[16];
    if (r == 0) {
        float s = 0.f;
#pragma unroll
        for (int k = 0; k < 16; ++k) s += red[k][f];
        pooled[f] = s / fmaxf((float)(hi - lo), 1.0f);
    }
    __syncthreads();
    if (threadIdx.x == 0) {
        float o[2];
        head_mlp(pooled, Wp1, bp1, Wp2, bp2, Wp3, bp3, o);
        out[4 * g + 0] = o[0]; out[4 * g + 1] = o[1];
    } else if (threadIdx.x == 1) {
        float o[2];
        head_mlp(pooled, Wt1, bt1, Wt2, bt2, Wt3, bt3, o);
        out[4 * g + 2] = o[0]; out[4 * g + 3] = o[1];
    }
}

extern "C" void kernel_launch(void* const* d_in, const int* in_sizes, int n_in,
                              void* d_out, int out_size, void* d_ws, size_t ws_size,
                              hipStream_t stream) {
    const float* X        = (const float*)d_in[0];
    const int*   ei       = (const int*)d_in[1];
    const float* ew       = (const float*)d_in[2];
    const int*   batching = (const int*)d_in[3];
    const float* W1  = (const float*)d_in[5];  const float* b1  = (const float*)d_in[6];
    const float* W2  = (const float*)d_in[7];  const float* b2  = (const float*)d_in[8];
    const float* Wp1 = (const float*)d_in[9];  const float* bp1 = (const float*)d_in[10];
    const float* Wp2 = (const float*)d_in[11]; const float* bp2 = (const float*)d_in[12];
    const float* Wp3 = (const float*)d_in[13]; const float* bp3 = (const float*)d_in[14];
    const float* Wt1 = (const float*)d_in[15]; const float* bt1 = (const float*)d_in[16];
    const float* Wt2 = (const float*)d_in[17]; const float* bt2 = (const float*)d_in[18];
    const float* Wt3 = (const float*)d_in[19]; const float* bt3 = (const float*)d_in[20];

    const int N = in_sizes[3];        // 262144 = 512 * 512
    const int E = in_sizes[2];        // 4194304
    const int G = out_size / 4;       // 1024
    const int* src = ei;
    const int* dst = ei + E;

    char* ws = (char*)d_ws;
    size_t off = 0;
    long long* coarse = (long long*)(ws + off); off += (size_t)NBUCK * BCAP * 8; // 41.9 MB
    long long* edata  = (long long*)(ws + off); off += (size_t)E * 8;            // 32 MB
    int*   bucketCursor = (int*)(ws + off);   off += NBUCK * 4;
    int*   bucketBase   = (int*)(ws + off);   off += NBUCK * 4;
    int*   row  = (int*)(ws + off);           off += (size_t)(N + 1) * 4;
    float* dinv = (float*)(ws + off);         off += (size_t)N * 4;
    _Float16* hhA = (_Float16*)(ws + off);    off += (size_t)N * 16;            // 4 MB
    _Float16* hhB = (_Float16*)(ws + off);    off += (size_t)N * 16;            // 4 MB
    // xA/xB overlay the dead coarse region (coarse unused after binB)
    float* xA = (float*)coarse;                                                 // 8 MB
    float* xB = (float*)(ws + (size_t)N * 32);                                  // 8 MB
    float* out = (float*)d_out;

    (void)hipMemsetAsync(bucketCursor, 0, NBUCK * 4, stream);

    const int tb = 256;
    binA_kernel<<<(E + CHUNK - 1) / CHUNK, tb, 0, stream>>>(src, dst, ew, bucketCursor, coarse, E);
    bscan_kernel<<<1, NBUCK, 0, stream>>>(bucketCursor, bucketBase, row, N, E);
    binB_kernel<<<NBUCK, tb, 0, stream>>>(bucketCursor, bucketBase, coarse, edata, row, dinv, N);
    node1_kernel<<<(N + tb - 1) / tb, tb, 0, stream>>>(X, W1, dinv, hhA, hhB, N);
    agg_kernel<<<(2 * N + tb - 1) / tb, tb, 0, stream>>>(row, edata, dinv, hhA, b1,     xA, N);
    agg_kernel<<<(2 * N + tb - 1) / tb, tb, 0, stream>>>(row, edata, dinv, hhB, b1 + 8, xB, N);
    node2_kernel<<<(N + tb - 1) / tb, tb, 0, stream>>>(W2, dinv, xA, xB, hhA, hhB, N);
    agg_kernel<<<(2 * N + tb - 1) / tb, tb, 0, stream>>>(row, edata, dinv, hhA, b2,     xA, N);
    agg_kernel<<<(2 * N + tb - 1) / tb, tb, 0, stream>>>(row, edata, dinv, hhB, b2 + 8, xB, N);
    pool_head_kernel<<<G, tb, 0, stream>>>(xA, xB, batching, N,
                                           Wp1, bp1, Wp2, bp2, Wp3, bp3,
                                           Wt1, bt1, Wt2, bt2, Wt3, bt3, out);
}

// Round 7
// 536.975 us; speedup vs baseline: 1.7243x; 1.0464x over previous
//
#include <hip/hip_runtime.h>
#include <hip/hip_fp16.h>

// GCN: 2x GCNConv + mean-pool + 2 MLP heads.
// Strategy R6: (1) binB sorts bucket into LDS, writes edata coalesced
// (R6 found 111MB write amplification from scattered 8B writes);
// (2) merged 16-feat fp16 hh (32B/node, 8MB) -> one agg per layer;
// (3) node2 fused into aggL1 epilogue (x1 stays in registers), aggL2
// emits y as fp16. deg computed in node1 from sorted runs (ldeg atomics gone).

#define NBUCK 512          // coarse buckets = dst >> 9
#define BCAP  10240        // slack capacity per bucket in global coarse
#define SCAP  8832         // LDS staging cap (mean 8192 + 7 sigma)
#define CHUNK 4096         // edges per binA block

typedef float    vfloat4 __attribute__((ext_vector_type(4)));
typedef _Float16 vhalf8  __attribute__((ext_vector_type(8)));

__device__ __forceinline__ float leaky(float x) { return x > 0.f ? x : 0.01f * x; }

// --- Pass A: bin edges by dst>>9; payload (src | ld<<18, ew) -------------
__global__ __launch_bounds__(256) void
binA_kernel(const int* __restrict__ src, const int* __restrict__ dst,
            const float* __restrict__ ew, int* __restrict__ bucketCursor,
            long long* __restrict__ coarse, int E) {
    __shared__ int lhist[NBUCK], lbase[NBUCK], lcur[NBUCK], gbase[NBUCK];
    __shared__ int tmp[256];
    __shared__ long long stag[CHUNK];
    __shared__ unsigned short sbuck[CHUNK];
    int t = threadIdx.x;
    int base = blockIdx.x * CHUNK;
    for (int b = t; b < NBUCK; b += 256) { lhist[b] = 0; lcur[b] = 0; }
    __syncthreads();
    int n = min(CHUNK, E - base);
    int myDst[16], mySrc[16]; float myEw[16];
#pragma unroll
    for (int k = 0; k < 16; ++k) {
        int j = t + k * 256;                       // coalesced
        if (j < n) {
            int d = dst[base + j];
            myDst[k] = d; mySrc[k] = src[base + j]; myEw[k] = ew[base + j];
            atomicAdd(&lhist[d >> 9], 1);
        } else myDst[k] = -1;
    }
    __syncthreads();
    tmp[t] = lhist[2 * t] + lhist[2 * t + 1];
    __syncthreads();
    for (int off = 1; off < 256; off <<= 1) {
        int v = (t >= off) ? tmp[t - off] : 0;
        __syncthreads();
        tmp[t] += v;
        __syncthreads();
    }
    int pb = (t == 0) ? 0 : tmp[t - 1];
    lbase[2 * t] = pb;
    lbase[2 * t + 1] = pb + lhist[2 * t];
    __syncthreads();
    for (int b = t; b < NBUCK; b += 256) {
        int c = lhist[b];
        gbase[b] = c ? atomicAdd(&bucketCursor[b], c) : 0;
    }
    for (int k = 0; k < 16; ++k) {
        int d = myDst[k];
        if (d >= 0) {
            int b = d >> 9;
            int p = lbase[b] + atomicAdd(&lcur[b], 1);
            unsigned int lo = (unsigned int)(mySrc[k] | ((d & 511) << 18));
            stag[p] = (long long)(((unsigned long long)__float_as_uint(myEw[k]) << 32) | lo);
            sbuck[p] = (unsigned short)b;
        }
    }
    __syncthreads();
    for (int j = t; j < n; j += 256) {
        int b = sbuck[j];
        __builtin_nontemporal_store(stag[j],
            &coarse[(size_t)b * BCAP + gbase[b] + (j - lbase[b])]);
    }
}

// --- scan bucket counts -> bucket bases (1 block x 512) ------------------
__global__ void bscan_kernel(const int* __restrict__ bucketCursor,
                             int* __restrict__ bucketBase, int* __restrict__ row,
                             int N, int E) {
    __shared__ int s[NBUCK];
    int t = threadIdx.x;
    int v = bucketCursor[t];
    s[t] = v;
    __syncthreads();
    for (int off = 1; off < NBUCK; off <<= 1) {
        int x = (t >= off) ? s[t - off] : 0;
        __syncthreads();
        s[t] += x;
        __syncthreads();
    }
    bucketBase[t] = s[t] - v;
    if (t == 0) row[N] = E;
}

// --- Pass B: fine sort in LDS; coalesced edata write; emit row -----------
__global__ __launch_bounds__(256) void
binB_kernel(const int* __restrict__ bucketCursor, const int* __restrict__ bucketBase,
            const long long* __restrict__ coarse, long long* __restrict__ edata,
            int* __restrict__ row, int N) {
    __shared__ int lhist[NBUCK], loff[NBUCK], lcur[NBUCK];
    __shared__ int tmp[256];
    __shared__ long long stag[SCAP];
    int b = blockIdx.x, t = threadIdx.x;
    for (int i = t; i < NBUCK; i += 256) { lhist[i] = 0; lcur[i] = 0; }
    __syncthreads();
    int cnt = min(bucketCursor[b], SCAP);
    const long long* cb = coarse + (size_t)b * BCAP;
    // pass 1: histogram (streaming read)
    for (int j = t; j < cnt; j += 256) {
        long long e = __builtin_nontemporal_load(cb + j);
        atomicAdd(&lhist[((int)e >> 18) & 511], 1);
    }
    __syncthreads();
    tmp[t] = lhist[2 * t] + lhist[2 * t + 1];
    __syncthreads();
    for (int off = 1; off < 256; off <<= 1) {
        int v = (t >= off) ? tmp[t - off] : 0;
        __syncthreads();
        tmp[t] += v;
        __syncthreads();
    }
    int pb = (t == 0) ? 0 : tmp[t - 1];
    loff[2 * t] = pb;
    loff[2 * t + 1] = pb + lhist[2 * t];
    __syncthreads();
    int gb = bucketBase[b];
    for (int i = t; i < NBUCK; i += 256)
        row[b * NBUCK + i] = gb + loff[i];
    // pass 2: scatter into LDS staging (repack: src low 18b, ew high)
    for (int j = t; j < cnt; j += 256) {
        long long e = __builtin_nontemporal_load(cb + j);
        int x = (int)e;
        int ld = (x >> 18) & 511;
        int pos = loff[ld] + atomicAdd(&lcur[ld], 1);
        stag[pos] = (long long)(((unsigned long long)e & 0xFFFFFFFF00000000ull)
                                | (unsigned)(x & 0x3FFFF));
    }
    __syncthreads();
    // pass 3: coalesced write-out
    for (int j = t; j < cnt; j += 256)
        __builtin_nontemporal_store(stag[j], &edata[gb + j]);
}

// --- node pass 1: deg from run; dinv; hh1 = (X@W1)*dinv (16 fp16) --------
__global__ __launch_bounds__(256) void
node1_kernel(const float* __restrict__ X, const float* __restrict__ W1,
             const int* __restrict__ row, const long long* __restrict__ edata,
             float* __restrict__ dinv, _Float16* __restrict__ hh, int N) {
    __shared__ float w[48];
    if (threadIdx.x < 48) w[threadIdx.x] = W1[threadIdx.x];
    __syncthreads();
    int i = blockIdx.x * blockDim.x + threadIdx.x;
    if (i >= N) return;
    int beg = row[i], end = row[i + 1];
    float deg = 1.0f;                              // self-loop
    for (int e = beg; e < end; ++e)
        deg += __uint_as_float((unsigned)((unsigned long long)edata[e] >> 32));
    float di = rsqrtf(deg);
    dinv[i] = di;
    float x0 = X[3 * i], x1 = X[3 * i + 1], x2 = X[3 * i + 2];
    union { _Float16 h[16]; vfloat4 v[2]; } u;
#pragma unroll
    for (int k = 0; k < 16; ++k)
        u.h[k] = (_Float16)((x0 * w[k] + x1 * w[16 + k] + x2 * w[32 + k]) * di);
    vfloat4* hp = (vfloat4*)(hh + (size_t)i * 16);
    hp[0] = u.v[0];
    hp[1] = u.v[1];
}

// --- merged agg (one thread/node, 16 feats in regs) ----------------------
// acc = sum_e ew*hh[src] + hh[i];  x = leaky(di*acc + bias)
// mode 0: h2 = x@Wmid; out hh2 = h2*di (fp16)    [layer-1 + node2 fused]
// mode 1: out y = x (fp16)                        [layer-2]
__global__ __launch_bounds__(256) void
agg_kernel(const int* __restrict__ row, const long long* __restrict__ edata,
           const float* __restrict__ dinv, const _Float16* __restrict__ hh,
           const float* __restrict__ bias, const float* __restrict__ Wmid,
           _Float16* __restrict__ out, int mode, int N) {
    __shared__ float w[256];
    __shared__ float bb[16];
    if (mode == 0) w[threadIdx.x] = Wmid[threadIdx.x];
    if (threadIdx.x < 16) bb[threadIdx.x] = bias[threadIdx.x];
    __syncthreads();
    int i = blockIdx.x * blockDim.x + threadIdx.x;
    if (i >= N) return;
    int beg = row[i], end = row[i + 1];
    const vhalf8* hp = (const vhalf8*)hh;          // 2 entries per node
    float acc[16];
    {
        vhalf8 s0 = hp[2 * i], s1 = hp[2 * i + 1];
#pragma unroll
        for (int k = 0; k < 8; ++k) { acc[k] = (float)s0[k]; acc[8 + k] = (float)s1[k]; }
    }
    for (int e = beg; e < end; ++e) {
        long long ev = edata[e];
        int s = (int)ev & 0x3FFFF;
        float wgt = __uint_as_float((unsigned)((unsigned long long)ev >> 32));
        vhalf8 g0 = hp[2 * s], g1 = hp[2 * s + 1];
#pragma unroll
        for (int k = 0; k < 8; ++k) {
            acc[k]     += (float)g0[k] * wgt;
            acc[8 + k] += (float)g1[k] * wgt;
        }
    }
    float di = dinv[i];
    float x[16];
#pragma unroll
    for (int k = 0; k < 16; ++k) x[k] = leaky(di * acc[k] + bb[k]);
    union { _Float16 h[16]; vfloat4 v[2]; } u;
    if (mode == 0) {
#pragma unroll
        for (int f = 0; f < 16; ++f) {
            float s = 0.f;
#pragma unroll
            for (int k = 0; k < 16; ++k) s += x[k] * w[k * 16 + f];
            u.h[f] = (_Float16)(s * di);
        }
    } else {
#pragma unroll
        for (int f = 0; f < 16; ++f) u.h[f] = (_Float16)x[f];
    }
    vfloat4* op = (vfloat4*)(out + (size_t)i * 16);
    __builtin_nontemporal_store(u.v[0], op);
    __builtin_nontemporal_store(u.v[1], op + 1);
}

// --- tiny MLP head: 16 ->16 ->16 ->2 -------------------------------------
__device__ void head_mlp(const float* pooled,
                         const float* __restrict__ Wa, const float* __restrict__ ba,
                         const float* __restrict__ Wb, const float* __restrict__ bb,
                         const float* __restrict__ Wc, const float* __restrict__ bc,
                         float* o) {
    float t[16], u[16];
#pragma unroll
    for (int f = 0; f < 16; ++f) {
        float a = ba[f];
        for (int k = 0; k < 16; ++k) a += pooled[k] * Wa[k * 16 + f];
        t[f] = leaky(a);
    }
#pragma unroll
    for (int f = 0; f < 16; ++f) {
        float a = bb[f];
        for (int k = 0; k < 16; ++k) a += t[k] * Wb[k * 16 + f];
        u[f] = leaky(a);
    }
    float o0 = bc[0], o1 = bc[1];
    for (int k = 0; k < 16; ++k) { o0 += u[k] * Wc[2 * k]; o1 += u[k] * Wc[2 * k + 1]; }
    o[0] = o0; o[1] = o1;
}

// --- pool (block per graph) + heads; y is fp16, post-activation ----------
__global__ void pool_head_kernel(const _Float16* __restrict__ y,
                                 const int* __restrict__ batching, int N,
                                 const float* __restrict__ Wp1, const float* __restrict__ bp1,
                                 const float* __restrict__ Wp2, const float* __restrict__ bp2,
                                 const float* __restrict__ Wp3, const float* __restrict__ bp3,
                                 const float* __restrict__ Wt1, const float* __restrict__ bt1,
                                 const float* __restrict__ Wt2, const float* __restrict__ bt2,
                                 const float* __restrict__ Wt3, const float* __restrict__ bt3,
                                 float* __restrict__ out) {
    int g = blockIdx.x;
    __shared__ int bounds[2];
    if (threadIdx.x < 2) {
        int v = g + (int)threadIdx.x;
        int lo = 0, hi = N;
        while (lo < hi) { int m = (lo + hi) >> 1; if (batching[m] < v) lo = m + 1; else hi = m; }
        bounds[threadIdx.x] = lo;
    }
    __syncthreads();
    int lo = bounds[0], hi = bounds[1];
    int f = threadIdx.x & 15, r = threadIdx.x >> 4;    // 16 rows x 16 features
    float acc = 0.f;
    for (int i = lo + r; i < hi; i += 16) acc += (float)y[(size_t)i * 16 + f];
    __shared__ float red[16][17];
    red[r][f] = acc;
    __syncthreads();
    __shared__ float pooled[16];
    if (r == 0) {
        float s = 0.f;
#pragma unroll
        for (int k = 0; k < 16; ++k) s += red[k][f];
        pooled[f] = s / fmaxf((float)(hi - lo), 1.0f);
    }
    __syncthreads();
    if (threadIdx.x == 0) {
        float o[2];
        head_mlp(pooled, Wp1, bp1, Wp2, bp2, Wp3, bp3, o);
        out[4 * g + 0] = o[0]; out[4 * g + 1] = o[1];
    } else if (threadIdx.x == 1) {
        float o[2];
        head_mlp(pooled, Wt1, bt1, Wt2, bt2, Wt3, bt3, o);
        out[4 * g + 2] = o[0]; out[4 * g + 3] = o[1];
    }
}

extern "C" void kernel_launch(void* const* d_in, const int* in_sizes, int n_in,
                              void* d_out, int out_size, void* d_ws, size_t ws_size,
                              hipStream_t stream) {
    const float* X        = (const float*)d_in[0];
    const int*   ei       = (const int*)d_in[1];
    const float* ew       = (const float*)d_in[2];
    const int*   batching = (const int*)d_in[3];
    const float* W1  = (const float*)d_in[5];  const float* b1  = (const float*)d_in[6];
    const float* W2  = (const float*)d_in[7];  const float* b2  = (const float*)d_in[8];
    const float* Wp1 = (const float*)d_in[9];  const float* bp1 = (const float*)d_in[10];
    const float* Wp2 = (const float*)d_in[11]; const float* bp2 = (const float*)d_in[12];
    const float* Wp3 = (const float*)d_in[13]; const float* bp3 = (const float*)d_in[14];
    const float* Wt1 = (const float*)d_in[15]; const float* bt1 = (const float*)d_in[16];
    const float* Wt2 = (const float*)d_in[17]; const float* bt2 = (const float*)d_in[18];
    const float* Wt3 = (const float*)d_in[19]; const float* bt3 = (const float*)d_in[20];

    const int N = in_sizes[3];        // 262144 = 512 * 512
    const int E = in_sizes[2];        // 4194304
    const int G = out_size / 4;       // 1024
    const int* src = ei;
    const int* dst = ei + E;

    char* ws = (char*)d_ws;
    size_t off = 0;
    long long* coarse = (long long*)(ws + off); off += (size_t)NBUCK * BCAP * 8; // 41.9 MB
    long long* edata  = (long long*)(ws + off); off += (size_t)E * 8;            // 32 MB
    int*   bucketCursor = (int*)(ws + off);   off += NBUCK * 4;
    int*   bucketBase   = (int*)(ws + off);   off += NBUCK * 4;
    int*   row  = (int*)(ws + off);           off += (size_t)(N + 1) * 4;
    float* dinv = (float*)(ws + off);         off += (size_t)N * 4;
    _Float16* hh1 = (_Float16*)(ws + off);    off += (size_t)N * 32;            // 8 MB
    _Float16* hh2 = (_Float16*)(ws + off);    off += (size_t)N * 32;            // 8 MB (hh2, then y)
    _Float16* y   = hh1;                       // layer-2 output overlays hh1

    float* out = (float*)d_out;

    (void)hipMemsetAsync(bucketCursor, 0, NBUCK * 4, stream);

    const int tb = 256;
    binA_kernel<<<(E + CHUNK - 1) / CHUNK, tb, 0, stream>>>(src, dst, ew, bucketCursor, coarse, E);
    bscan_kernel<<<1, NBUCK, 0, stream>>>(bucketCursor, bucketBase, row, N, E);
    binB_kernel<<<NBUCK, tb, 0, stream>>>(bucketCursor, bucketBase, coarse, edata, row, N);
    node1_kernel<<<(N + tb - 1) / tb, tb, 0, stream>>>(X, W1, row, edata, dinv, hh1, N);
    agg_kernel<<<(N + tb - 1) / tb, tb, 0, stream>>>(row, edata, dinv, hh1, b1, W2, hh2, 0, N);
    agg_kernel<<<(N + tb - 1) / tb, tb, 0, stream>>>(row, edata, dinv, hh2, b2, W2, y,   1, N);
    pool_head_kernel<<<G, tb, 0, stream>>>(y, batching, N,
                                           Wp1, bp1, Wp2, bp2, Wp3, bp3,
                                           Wt1, bt1, Wt2, bt2, Wt3, bt3, out);
}

// Round 8
// 512.291 us; speedup vs baseline: 1.8074x; 1.0482x over previous
//
#include <hip/hip_runtime.h>
#include <hip/hip_fp16.h>

// GCN: 2x GCNConv + mean-pool + 2 MLP heads.
// Strategy R8: feature-split fp16 gather restored (two 4 MB half-arrays,
// each fully per-XCD-L2 resident; R7's merged 8 MB array caused 466 MB
// fetch = HBM random-fill bound). nt edata loads in agg; fp16 x buffers;
// dinv computed in binB from sorted LDS runs (no atomics, node1 cheap).

#define NBUCK 512          // coarse buckets = dst >> 9
#define BCAP  10240        // slack capacity per bucket in global coarse
#define SCAP  8832         // LDS staging cap (mean 8192 + 7 sigma)
#define CHUNK 4096         // edges per binA block

typedef float    vfloat4 __attribute__((ext_vector_type(4)));
typedef _Float16 vhalf8  __attribute__((ext_vector_type(8)));

__device__ __forceinline__ float leaky(float x) { return x > 0.f ? x : 0.01f * x; }

// --- Pass A: bin edges by dst>>9; payload (src | ld<<18, ew) -------------
__global__ __launch_bounds__(256) void
binA_kernel(const int* __restrict__ src, const int* __restrict__ dst,
            const float* __restrict__ ew, int* __restrict__ bucketCursor,
            long long* __restrict__ coarse, int E) {
    __shared__ int lhist[NBUCK], lbase[NBUCK], lcur[NBUCK], gbase[NBUCK];
    __shared__ int tmp[256];
    __shared__ long long stag[CHUNK];
    __shared__ unsigned short sbuck[CHUNK];
    int t = threadIdx.x;
    int base = blockIdx.x * CHUNK;
    for (int b = t; b < NBUCK; b += 256) { lhist[b] = 0; lcur[b] = 0; }
    __syncthreads();
    int n = min(CHUNK, E - base);
    int myDst[16], mySrc[16]; float myEw[16];
#pragma unroll
    for (int k = 0; k < 16; ++k) {
        int j = t + k * 256;                       // coalesced
        if (j < n) {
            int d = dst[base + j];
            myDst[k] = d; mySrc[k] = src[base + j]; myEw[k] = ew[base + j];
            atomicAdd(&lhist[d >> 9], 1);
        } else myDst[k] = -1;
    }
    __syncthreads();
    tmp[t] = lhist[2 * t] + lhist[2 * t + 1];
    __syncthreads();
    for (int off = 1; off < 256; off <<= 1) {
        int v = (t >= off) ? tmp[t - off] : 0;
        __syncthreads();
        tmp[t] += v;
        __syncthreads();
    }
    int pb = (t == 0) ? 0 : tmp[t - 1];
    lbase[2 * t] = pb;
    lbase[2 * t + 1] = pb + lhist[2 * t];
    __syncthreads();
    for (int b = t; b < NBUCK; b += 256) {
        int c = lhist[b];
        gbase[b] = c ? atomicAdd(&bucketCursor[b], c) : 0;
    }
    for (int k = 0; k < 16; ++k) {
        int d = myDst[k];
        if (d >= 0) {
            int b = d >> 9;
            int p = lbase[b] + atomicAdd(&lcur[b], 1);
            unsigned int lo = (unsigned int)(mySrc[k] | ((d & 511) << 18));
            stag[p] = (long long)(((unsigned long long)__float_as_uint(myEw[k]) << 32) | lo);
            sbuck[p] = (unsigned short)b;
        }
    }
    __syncthreads();
    for (int j = t; j < n; j += 256) {
        int b = sbuck[j];
        __builtin_nontemporal_store(stag[j],
            &coarse[(size_t)b * BCAP + gbase[b] + (j - lbase[b])]);
    }
}

// --- scan bucket counts -> bucket bases (1 block x 512) ------------------
__global__ void bscan_kernel(const int* __restrict__ bucketCursor,
                             int* __restrict__ bucketBase, int* __restrict__ row,
                             int N, int E) {
    __shared__ int s[NBUCK];
    int t = threadIdx.x;
    int v = bucketCursor[t];
    s[t] = v;
    __syncthreads();
    for (int off = 1; off < NBUCK; off <<= 1) {
        int x = (t >= off) ? s[t - off] : 0;
        __syncthreads();
        s[t] += x;
        __syncthreads();
    }
    bucketBase[t] = s[t] - v;
    if (t == 0) row[N] = E;
}

// --- Pass B: fine sort in LDS; coalesced edata write; emit row + dinv ----
__global__ __launch_bounds__(256) void
binB_kernel(const int* __restrict__ bucketCursor, const int* __restrict__ bucketBase,
            const long long* __restrict__ coarse, long long* __restrict__ edata,
            int* __restrict__ row, float* __restrict__ dinv, int N) {
    __shared__ int lhist[NBUCK], loff[NBUCK], lcur[NBUCK];
    __shared__ int tmp[256];
    __shared__ long long stag[SCAP];
    int b = blockIdx.x, t = threadIdx.x;
    for (int i = t; i < NBUCK; i += 256) { lhist[i] = 0; lcur[i] = 0; }
    __syncthreads();
    int cnt = min(bucketCursor[b], SCAP);
    const long long* cb = coarse + (size_t)b * BCAP;
    // pass 1: histogram (streaming read)
    for (int j = t; j < cnt; j += 256) {
        long long e = __builtin_nontemporal_load(cb + j);
        atomicAdd(&lhist[((int)e >> 18) & 511], 1);
    }
    __syncthreads();
    tmp[t] = lhist[2 * t] + lhist[2 * t + 1];
    __syncthreads();
    for (int off = 1; off < 256; off <<= 1) {
        int v = (t >= off) ? tmp[t - off] : 0;
        __syncthreads();
        tmp[t] += v;
        __syncthreads();
    }
    int pb = (t == 0) ? 0 : tmp[t - 1];
    loff[2 * t] = pb;
    loff[2 * t + 1] = pb + lhist[2 * t];
    __syncthreads();
    int gb = bucketBase[b];
    for (int i = t; i < NBUCK; i += 256)
        row[b * NBUCK + i] = gb + loff[i];
    // pass 2: scatter into LDS staging (repack: src low 18b, ew high)
    for (int j = t; j < cnt; j += 256) {
        long long e = __builtin_nontemporal_load(cb + j);
        int x = (int)e;
        int ld = (x >> 18) & 511;
        int pos = loff[ld] + atomicAdd(&lcur[ld], 1);
        stag[pos] = (long long)(((unsigned long long)e & 0xFFFFFFFF00000000ull)
                                | (unsigned)(x & 0x3FFFF));
    }
    __syncthreads();
    // pass 3: per-node run sum -> dinv (no atomics: runs are contiguous)
    for (int i = t; i < NBUCK; i += 256) {
        int lo = loff[i];
        int hi = (i == NBUCK - 1) ? cnt : loff[i + 1];
        float deg = 1.0f;                          // self-loop weight
        for (int j = lo; j < hi; ++j)
            deg += __uint_as_float((unsigned)((unsigned long long)stag[j] >> 32));
        dinv[b * NBUCK + i] = rsqrtf(deg);
    }
    // pass 4: coalesced write-out
    for (int j = t; j < cnt; j += 256)
        __builtin_nontemporal_store(stag[j], &edata[gb + j]);
}

// --- node pass 1: hh1 = (X@W1)*dinv, fp16, feature-split halves ----------
__global__ __launch_bounds__(256) void
node1_kernel(const float* __restrict__ X, const float* __restrict__ W1,
             const float* __restrict__ dinv,
             _Float16* __restrict__ hhA, _Float16* __restrict__ hhB, int N) {
    __shared__ float w[48];
    if (threadIdx.x < 48) w[threadIdx.x] = W1[threadIdx.x];
    __syncthreads();
    int i = blockIdx.x * blockDim.x + threadIdx.x;
    if (i >= N) return;
    float di = dinv[i];
    float x0 = X[3 * i], x1 = X[3 * i + 1], x2 = X[3 * i + 2];
    union { _Float16 h[8]; vfloat4 v; } ua, ub;
#pragma unroll
    for (int k = 0; k < 8; ++k)
        ua.h[k] = (_Float16)((x0 * w[k] + x1 * w[16 + k] + x2 * w[32 + k]) * di);
#pragma unroll
    for (int k = 0; k < 8; ++k)
        ub.h[k] = (_Float16)((x0 * w[8 + k] + x1 * w[24 + k] + x2 * w[40 + k]) * di);
    ((vfloat4*)hhA)[i] = ua.v;
    ((vfloat4*)hhB)[i] = ub.v;
}

// --- half-feature gather agg: 1 thread/node, 8 feats in regs -------------
// x[i,f] = leaky( dinv_i*(sum_e ew*hh[src,f] + hh[i,f]) + bias8[f] ), fp16 out
__global__ __launch_bounds__(256) void
agg_kernel(const int* __restrict__ row, const long long* __restrict__ edata,
           const float* __restrict__ dinv, const _Float16* __restrict__ hh,
           const float* __restrict__ bias8, _Float16* __restrict__ xout, int N) {
    __shared__ float bb[8];
    if (threadIdx.x < 8) bb[threadIdx.x] = bias8[threadIdx.x];
    __syncthreads();
    int i = blockIdx.x * blockDim.x + threadIdx.x;
    if (i >= N) return;
    int beg = row[i], end = row[i + 1];
    const vhalf8* hp = (const vhalf8*)hh;
    float acc[8];
    {
        vhalf8 self = hp[i];
#pragma unroll
        for (int k = 0; k < 8; ++k) acc[k] = (float)self[k];
    }
    int e = beg;
    for (; e + 2 <= end; e += 2) {
        long long ev0 = __builtin_nontemporal_load(edata + e);
        long long ev1 = __builtin_nontemporal_load(edata + e + 1);
        int s0 = (int)ev0 & 0x3FFFF, s1 = (int)ev1 & 0x3FFFF;
        float w0 = __uint_as_float((unsigned)((unsigned long long)ev0 >> 32));
        float w1 = __uint_as_float((unsigned)((unsigned long long)ev1 >> 32));
        vhalf8 g0 = hp[s0], g1 = hp[s1];
#pragma unroll
        for (int k = 0; k < 8; ++k) acc[k] += (float)g0[k] * w0 + (float)g1[k] * w1;
    }
    if (e < end) {
        long long ev = __builtin_nontemporal_load(edata + e);
        int s = (int)ev & 0x3FFFF;
        float w = __uint_as_float((unsigned)((unsigned long long)ev >> 32));
        vhalf8 g = hp[s];
#pragma unroll
        for (int k = 0; k < 8; ++k) acc[k] += (float)g[k] * w;
    }
    float di = dinv[i];
    union { _Float16 h[8]; vfloat4 v; } u;
#pragma unroll
    for (int k = 0; k < 8; ++k) u.h[k] = (_Float16)leaky(di * acc[k] + bb[k]);
    __builtin_nontemporal_store(u.v, (vfloat4*)(xout + (size_t)i * 8));
}

// --- node pass 2: h2 = x1@W2; hh2 = h2*dinv, fp16, split -----------------
__global__ __launch_bounds__(256) void
node2_kernel(const float* __restrict__ W2, const float* __restrict__ dinv,
             const _Float16* __restrict__ xA, const _Float16* __restrict__ xB,
             _Float16* __restrict__ hhA, _Float16* __restrict__ hhB, int N) {
    __shared__ float w[256];
    w[threadIdx.x] = W2[threadIdx.x];                // blockDim == 256
    __syncthreads();
    int i = blockIdx.x * blockDim.x + threadIdx.x;
    if (i >= N) return;
    float x[16];
    {
        vhalf8 a = ((const vhalf8*)xA)[i], b = ((const vhalf8*)xB)[i];
#pragma unroll
        for (int k = 0; k < 8; ++k) { x[k] = (float)a[k]; x[8 + k] = (float)b[k]; }
    }
    float di = dinv[i];
    union { _Float16 h[8]; vfloat4 v; } ua, ub;
#pragma unroll
    for (int f = 0; f < 8; ++f) {
        float s = 0.f;
#pragma unroll
        for (int k = 0; k < 16; ++k) s += x[k] * w[k * 16 + f];
        ua.h[f] = (_Float16)(s * di);
    }
#pragma unroll
    for (int f = 0; f < 8; ++f) {
        float s = 0.f;
#pragma unroll
        for (int k = 0; k < 16; ++k) s += x[k] * w[k * 16 + 8 + f];
        ub.h[f] = (_Float16)(s * di);
    }
    ((vfloat4*)hhA)[i] = ua.v;
    ((vfloat4*)hhB)[i] = ub.v;
}

// --- tiny MLP head: 16 ->16 ->16 ->2 -------------------------------------
__device__ void head_mlp(const float* pooled,
                         const float* __restrict__ Wa, const float* __restrict__ ba,
                         const float* __restrict__ Wb, const float* __restrict__ bb,
                         const float* __restrict__ Wc, const float* __restrict__ bc,
                         float* o) {
    float t[16], u[16];
#pragma unroll
    for (int f = 0; f < 16; ++f) {
        float a = ba[f];
        for (int k = 0; k < 16; ++k) a += pooled[k] * Wa[k * 16 + f];
        t[f] = leaky(a);
    }
#pragma unroll
    for (int f = 0; f < 16; ++f) {
        float a = bb[f];
        for (int k = 0; k < 16; ++k) a += t[k] * Wb[k * 16 + f];
        u[f] = leaky(a);
    }
    float o0 = bc[0], o1 = bc[1];
    for (int k = 0; k < 16; ++k) { o0 += u[k] * Wc[2 * k]; o1 += u[k] * Wc[2 * k + 1]; }
    o[0] = o0; o[1] = o1;
}

// --- pool (block per graph) + heads; y split fp16, post-activation -------
__global__ void pool_head_kernel(const _Float16* __restrict__ yA,
                                 const _Float16* __restrict__ yB,
                                 const int* __restrict__ batching, int N,
                                 const float* __restrict__ Wp1, const float* __restrict__ bp1,
                                 const float* __restrict__ Wp2, const float* __restrict__ bp2,
                                 const float* __restrict__ Wp3, const float* __restrict__ bp3,
                                 const float* __restrict__ Wt1, const float* __restrict__ bt1,
                                 const float* __restrict__ Wt2, const float* __restrict__ bt2,
                                 const float* __restrict__ Wt3, const float* __restrict__ bt3,
                                 float* __restrict__ out) {
    int g = blockIdx.x;
    __shared__ int bounds[2];
    if (threadIdx.x < 2) {
        int v = g + (int)threadIdx.x;
        int lo = 0, hi = N;
        while (lo < hi) { int m = (lo + hi) >> 1; if (batching[m] < v) lo = m + 1; else hi = m; }
        bounds[threadIdx.x] = lo;
    }
    __syncthreads();
    int lo = bounds[0], hi = bounds[1];
    int f = threadIdx.x & 15, r = threadIdx.x >> 4;    // 16 rows x 16 features
    const _Float16* yb = (f < 8) ? yA : yB;
    int fo = f & 7;
    float acc = 0.f;
    for (int i = lo + r; i < hi; i += 16) acc += (float)yb[(size_t)i * 8 + fo];
    __shared__ float red[16][17];
    red[r][f] = acc;
    __syncthreads();
    __shared__ float pooled[16];
    if (r == 0) {
        float s = 0.f;
#pragma unroll
        for (int k = 0; k < 16; ++k) s += red[k][f];
        pooled[f] = s / fmaxf((float)(hi - lo), 1.0f);
    }
    __syncthreads();
    if (threadIdx.x == 0) {
        float o[2];
        head_mlp(pooled, Wp1, bp1, Wp2, bp2, Wp3, bp3, o);
        out[4 * g + 0] = o[0]; out[4 * g + 1] = o[1];
    } else if (threadIdx.x == 1) {
        float o[2];
        head_mlp(pooled, Wt1, bt1, Wt2, bt2, Wt3, bt3, o);
        out[4 * g + 2] = o[0]; out[4 * g + 3] = o[1];
    }
}

extern "C" void kernel_launch(void* const* d_in, const int* in_sizes, int n_in,
                              void* d_out, int out_size, void* d_ws, size_t ws_size,
                              hipStream_t stream) {
    const float* X        = (const float*)d_in[0];
    const int*   ei       = (const int*)d_in[1];
    const float* ew       = (const float*)d_in[2];
    const int*   batching = (const int*)d_in[3];
    const float* W1  = (const float*)d_in[5];  const float* b1  = (const float*)d_in[6];
    const float* W2  = (const float*)d_in[7];  const float* b2  = (const float*)d_in[8];
    const float* Wp1 = (const float*)d_in[9];  const float* bp1 = (const float*)d_in[10];
    const float* Wp2 = (const float*)d_in[11]; const float* bp2 = (const float*)d_in[12];
    const float* Wp3 = (const float*)d_in[13]; const float* bp3 = (const float*)d_in[14];
    const float* Wt1 = (const float*)d_in[15]; const float* bt1 = (const float*)d_in[16];
    const float* Wt2 = (const float*)d_in[17]; const float* bt2 = (const float*)d_in[18];
    const float* Wt3 = (const float*)d_in[19]; const float* bt3 = (const float*)d_in[20];

    const int N = in_sizes[3];        // 262144 = 512 * 512
    const int E = in_sizes[2];        // 4194304
    const int G = out_size / 4;       // 1024
    const int* src = ei;
    const int* dst = ei + E;

    char* ws = (char*)d_ws;
    size_t off = 0;
    long long* coarse = (long long*)(ws + off); off += (size_t)NBUCK * BCAP * 8; // 41.9 MB
    long long* edata  = (long long*)(ws + off); off += (size_t)E * 8;            // 32 MB
    int*   bucketCursor = (int*)(ws + off);   off += NBUCK * 4;
    int*   bucketBase   = (int*)(ws + off);   off += NBUCK * 4;
    int*   row  = (int*)(ws + off);           off += (size_t)(N + 1) * 4;
    float* dinv = (float*)(ws + off);         off += (size_t)N * 4;
    _Float16* hhA = (_Float16*)(ws + off);    off += (size_t)N * 16;            // 4 MB (hh1A -> hh2A)
    _Float16* hhB = (_Float16*)(ws + off);    off += (size_t)N * 16;            // 4 MB
    _Float16* xA  = (_Float16*)(ws + off);    off += (size_t)N * 16;            // 4 MB (x1A -> yA)
    _Float16* xB  = (_Float16*)(ws + off);    off += (size_t)N * 16;            // 4 MB
    float* out = (float*)d_out;

    (void)hipMemsetAsync(bucketCursor, 0, NBUCK * 4, stream);

    const int tb = 256;
    binA_kernel<<<(E + CHUNK - 1) / CHUNK, tb, 0, stream>>>(src, dst, ew, bucketCursor, coarse, E);
    bscan_kernel<<<1, NBUCK, 0, stream>>>(bucketCursor, bucketBase, row, N, E);
    binB_kernel<<<NBUCK, tb, 0, stream>>>(bucketCursor, bucketBase, coarse, edata, row, dinv, N);
    node1_kernel<<<(N + tb - 1) / tb, tb, 0, stream>>>(X, W1, dinv, hhA, hhB, N);
    agg_kernel<<<(N + tb - 1) / tb, tb, 0, stream>>>(row, edata, dinv, hhA, b1,     xA, N);
    agg_kernel<<<(N + tb - 1) / tb, tb, 0, stream>>>(row, edata, dinv, hhB, b1 + 8, xB, N);
    node2_kernel<<<(N + tb - 1) / tb, tb, 0, stream>>>(W2, dinv, xA, xB, hhA, hhB, N);
    agg_kernel<<<(N + tb - 1) / tb, tb, 0, stream>>>(row, edata, dinv, hhA, b2,     xA, N);
    agg_kernel<<<(N + tb - 1) / tb, tb, 0, stream>>>(row, edata, dinv, hhB, b2 + 8, xB, N);
    pool_head_kernel<<<G, tb, 0, stream>>>(xA, xB, batching, N,
                                           Wp1, bp1, Wp2, bp2, Wp3, bp3,
                                           Wt1, bt1, Wt2, bt2, Wt3, bt3, out);
}